// Round 1
// 127.979 us; speedup vs baseline: 1.1137x; 1.1137x over previous
//
#include <hip/hip_runtime.h>

// KAN layer as one fused fp16 MFMA GEMM:
//   out[b,i] = sum_j [ neg*bw*pw + pos*bw + sum_k basis[b,j,k]*sw[i,j]*sc[i,j,k] ]
// A  [2048 x 11264] fp16 : per j, 22 slots = {20 basis (5 nonzero), neg, pos}
// Ct [ 512 x 11264] fp16 : per j, 22 slots = {sw*sc[0..19], bw*pw, bw}   (B^T layout)
// R5: (a) KSPLIT=8 with NON-ATOMIC partial buffers + reduce8 kernel — kills the
//     11.5M device-scope atomicAdds (WRITE_SIZE showed 11x write-through, the
//     L2 atomic units were the bottleneck at ~186 G atomics/s);
//     (b) K-loop re-pipelined: 3 LDS buffers, loads issued 2 chunks ahead,
//     counted s_waitcnt vmcnt(4) + raw s_barrier (T3/T4 — never drain vmcnt
//     to 0 in the main loop), s_setprio(1) around the 16-MFMA cluster (T5).
//     Atomic KSPLIT=11 path kept (also pipelined) as runtime ws fallback.
// ws usage: A = 46.1 MB, Ct = 11.5 MB, partials = 33.6 MB (91.2 MB total).

typedef _Float16 half_t;
typedef __attribute__((ext_vector_type(8))) _Float16 half8;
typedef __attribute__((ext_vector_type(4))) float floatx4;

#define B_DIM   2048
#define J_DIM   512
#define O_DIM   512
#define SLOTS   22
#define K_TOT   (J_DIM * SLOTS)      // 11264
#define MTILE   128
#define NTILE   128
#define BK      32
#define KSPLIT_P 8                   // partials path
#define KSPLIT_A 11                  // atomic fallback path
#define ZERO_BLKS 64                 // blocks zeroing the 4 MB output

// ---------------------------------------------------------------------------
// Quartic B-spline local basis, uniform knots g_i = -1.5 + i*(3.125/24).
// (Reference quirk: linspace(-1.5, 1.625, 25) -> spacing 3.125/24, NOT 0.125.)
// m in [3,19]; window k = m-4 .. m, entries with k<0 dropped.
__device__ __forceinline__ void bspline5(float xc, int& k0, float Nv[5]) {
    const float invS = 7.68f;              // 24/3.125 (exact ratio)
    float u = (xc + 1.5f) * invS;          // knot units
    int m = (int)u;
    m = min(max(m, 3), 19);
    k0 = m - 4;
    Nv[0] = 1.f; Nv[1] = 0.f; Nv[2] = 0.f; Nv[3] = 0.f; Nv[4] = 0.f;
#pragma unroll
    for (int d = 1; d <= 4; ++d) {
        float nw[5];
        float inv_d = 1.0f / (float)d;
#pragma unroll
        for (int r = 0; r < 5; ++r) {
            if (r > d) { nw[r] = 0.f; continue; }
            float kk = (float)(m - d + r);
            float acc = 0.f;
            if (r >= 1) acc += (u - kk) * Nv[r - 1];
            if (r < d)  acc += (kk + (float)(d + 1) - u) * Nv[r];
            nw[r] = acc * inv_d;
        }
#pragma unroll
        for (int r = 0; r < 5; ++r) Nv[r] = nw[r];
    }
}

// ---------------------------------------------------------------------------
// Fused prep: blocks [0,64) zero the output; [64, 64+512) build Ct rows;
// [64+512, 64+512+2048) build A rows.  (Unchanged from R4 — isolated so the
// gemm delta attributes cleanly; prep counters will surface in top-5 now.)
__global__ __launch_bounds__(256) void prep_all(const float* __restrict__ x,
                                                const float* __restrict__ pw,
                                                const float* __restrict__ bw,
                                                const float* __restrict__ sw,
                                                const float* __restrict__ sc,
                                                half_t* __restrict__ A,
                                                half_t* __restrict__ Ct,
                                                float* __restrict__ out) {
    __shared__ half_t rec[J_DIM * SLOTS];  // 22528 B
    int bid = blockIdx.x;
    int t = threadIdx.x;

    if (bid < ZERO_BLKS) {
        float4* o = (float4*)out;
        int base = bid * 4096;
#pragma unroll
        for (int i = 0; i < 16; ++i)
            o[base + i * 256 + t] = make_float4(0.f, 0.f, 0.f, 0.f);
        return;
    }

    if (bid < ZERO_BLKS + O_DIM) {
        // prep_C: fold spline_weight into coeffs + base slots. sc row is
        // 16B-aligned per (i,j): ij*20 floats = ij*80 B.
        int i = bid - ZERO_BLKS;
#pragma unroll
        for (int jj = 0; jj < 2; ++jj) {
            int j = t + jj * 256;
            size_t ij = (size_t)i * J_DIM + j;
            float s = sw[ij], b = bw[ij], p = pw[ij];
            const float4* scp4 = (const float4*)(sc + ij * 20);
            half_t* r = rec + j * SLOTS;
#pragma unroll
            for (int v = 0; v < 5; ++v) {
                float4 c4 = scp4[v];
                r[v * 4 + 0] = (half_t)(s * c4.x);
                r[v * 4 + 1] = (half_t)(s * c4.y);
                r[v * 4 + 2] = (half_t)(s * c4.z);
                r[v * 4 + 3] = (half_t)(s * c4.w);
            }
            r[20] = (half_t)(b * p);
            r[21] = (half_t)b;
        }
        __syncthreads();
        const uint4* src = (const uint4*)rec;
        uint4* dst = (uint4*)(Ct + (size_t)i * K_TOT);
        for (int idx = t; idx < (J_DIM * SLOTS * 2) / 16; idx += 256) dst[idx] = src[idx];
        return;
    }

    // prep_A: basis record per (b, j)
    int b = bid - ZERO_BLKS - O_DIM;
#pragma unroll
    for (int jj = 0; jj < 2; ++jj) {
        int j = t + jj * 256;
        float xv = x[(size_t)b * J_DIM + j];
        float xc = fminf(fmaxf(xv, -1.f), 1.f);
        float pos = fmaxf(xc, 0.f);
        float neg = xc - pos;
        int k0; float Nv[5];
        bspline5(xc, k0, Nv);
        half_t* r = rec + j * SLOTS;
#pragma unroll
        for (int k = 0; k < 20; ++k) r[k] = (half_t)0.f;
#pragma unroll
        for (int rr = 0; rr < 5; ++rr) {
            int k = k0 + rr;
            if (k >= 0) r[k] = (half_t)Nv[rr];   // k <= 19 guaranteed (k0 <= 15)
        }
        r[20] = (half_t)neg;
        r[21] = (half_t)pos;
    }
    __syncthreads();
    const uint4* src = (const uint4*)rec;
    uint4* dst = (uint4*)(A + (size_t)b * K_TOT);
    for (int i = t; i < (J_DIM * SLOTS * 2) / 16; i += 256) dst[i] = src[i];
}

// ---------------------------------------------------------------------------
// GEMM: Grid (16, 4, KSPLIT), 256 thr. 3-deep LDS pipeline:
//   prologue issues chunks 0,1; iter c waits vmcnt(4) (chunk c's 4 loads done,
//   chunk c+1's still flying), raw s_barrier, issues chunk c+2, then
//   ds_read + 16 MFMA under setprio(1). vmcnt never drains to 0 in the loop
//   (T4) — the old __syncthreads carried an implicit vmcnt(0) drain every
//   chunk, stalling ~full load latency 32x/block.
// XOR swizzle on the global source k-quad kills fragment-read conflicts (R3: 0).
// OUTMODE 0: plain stores into per-z partial buffers (no atomics).
// OUTMODE 1: legacy atomicAdd into out (ws-constrained fallback).
template<int KSPLIT_T, int OUTMODE>
__global__ __launch_bounds__(256, 3) void gemm_f16(const half_t* __restrict__ A,
                                                   const half_t* __restrict__ Bt,
                                                   float* __restrict__ out) {
    constexpr int KS_LEN_T = K_TOT / KSPLIT_T;
    constexpr int KCH_T = KS_LEN_T / BK;
    static_assert(KS_LEN_T % BK == 0, "k-split must be BK-aligned");
    static_assert(KCH_T >= 2, "pipeline needs >= 2 chunks");

    __shared__ half_t As[3][MTILE * BK];   // 3 x 8 KB
    __shared__ half_t Bs[3][NTILE * BK];   // 3 x 8 KB   (48 KB total -> 3 blk/CU)

    int m0 = blockIdx.x * MTILE;
    int n0 = blockIdx.y * NTILE;
    int ks = blockIdx.z * KS_LEN_T;     // halfs; KS_LEN_T*2 B is 16B-aligned

    int t = threadIdx.x;
    int w = t >> 6;          // wave 0..3
    int l = t & 63;
    int wm = w >> 1, wn = w & 1;

    floatx4 acc[4][4] = {};

    int lrow = l >> 2;                            // 0..15: row within 16-row chunk
    int lkof = (((l & 3) ^ ((l >> 3) & 3)) * 8);  // swizzled k-quad source offset

    const half_t* gA = A + (size_t)m0 * K_TOT + ks;
    const half_t* gB = Bt + (size_t)n0 * K_TOT + ks;

    int q = l >> 4;               // 0..3
    int fr = l & 15;              // 0..15
    int qs = (q ^ ((fr >> 1) & 3)) * 8;  // swizzled read offset (elements)

// 4 global_load_lds per thread per chunk (2 A + 2 B) -> vmcnt counts in 4s.
#define ISSUE_LOADS(c, p)                                                     \
    {                                                                         \
        int kb = (c) * BK;                                                    \
        _Pragma("unroll")                                                     \
        for (int n = 0; n < 2; ++n) {                                         \
            int r = (w * 2 + n) * 16 + lrow;                                  \
            __builtin_amdgcn_global_load_lds(                                 \
                (const __attribute__((address_space(1))) unsigned int*)       \
                    (gA + (size_t)r * K_TOT + kb + lkof),                     \
                (__attribute__((address_space(3))) unsigned int*)             \
                    (&As[p][0] + (w * 2 + n) * 512),                          \
                16, 0, 0);                                                    \
            __builtin_amdgcn_global_load_lds(                                 \
                (const __attribute__((address_space(1))) unsigned int*)       \
                    (gB + (size_t)r * K_TOT + kb + lkof),                     \
                (__attribute__((address_space(3))) unsigned int*)             \
                    (&Bs[p][0] + (w * 2 + n) * 512),                          \
                16, 0, 0);                                                    \
        }                                                                     \
    }

    ISSUE_LOADS(0, 0)
    ISSUE_LOADS(1, 1)

    int pb = 0;                              // consume buffer = c % 3
    for (int c = 0; c < KCH_T; ++c) {
        if (c + 2 < KCH_T) {
            // 8 outstanding (c, c+1); keep c+1's 4 flying across the barrier.
            asm volatile("s_waitcnt vmcnt(4)" ::: "memory");
            __builtin_amdgcn_s_barrier();
            int pn = pb + 2; if (pn >= 3) pn -= 3;
            ISSUE_LOADS(c + 2, pn)
        } else if (c + 2 == KCH_T) {
            asm volatile("s_waitcnt vmcnt(4)" ::: "memory");
            __builtin_amdgcn_s_barrier();
        } else {
            asm volatile("s_waitcnt vmcnt(0)" ::: "memory");
            __builtin_amdgcn_s_barrier();
        }

        half8 af[4], bf[4];
#pragma unroll
        for (int mt = 0; mt < 4; ++mt)
            af[mt] = *(const half8*)(&As[pb][0] + (wm * 64 + mt * 16 + fr) * BK + qs);
#pragma unroll
        for (int nt = 0; nt < 4; ++nt)
            bf[nt] = *(const half8*)(&Bs[pb][0] + (wn * 64 + nt * 16 + fr) * BK + qs);

        __builtin_amdgcn_s_setprio(1);
#pragma unroll
        for (int mt = 0; mt < 4; ++mt)
#pragma unroll
            for (int nt = 0; nt < 4; ++nt)
                acc[mt][nt] = __builtin_amdgcn_mfma_f32_16x16x32_f16(
                    af[mt], bf[nt], acc[mt][nt], 0, 0, 0);
        __builtin_amdgcn_s_setprio(0);

        if (++pb == 3) pb = 0;
    }
#undef ISSUE_LOADS

    // epilogue: C/D layout col = lane&15, row = (lane>>4)*4 + reg (m89-verified)
    if (OUTMODE == 0) {
        float* dst = out + (size_t)blockIdx.z * ((size_t)B_DIM * O_DIM);
#pragma unroll
        for (int mt = 0; mt < 4; ++mt)
#pragma unroll
            for (int nt = 0; nt < 4; ++nt) {
                int rr = m0 + wm * 64 + mt * 16 + q * 4;
                int cc = n0 + wn * 64 + nt * 16 + fr;
#pragma unroll
                for (int r = 0; r < 4; ++r)
                    dst[(size_t)(rr + r) * O_DIM + cc] = acc[mt][nt][r];
            }
    } else {
#pragma unroll
        for (int mt = 0; mt < 4; ++mt)
#pragma unroll
            for (int nt = 0; nt < 4; ++nt) {
                int rr = m0 + wm * 64 + mt * 16 + q * 4;
                int cc = n0 + wn * 64 + nt * 16 + fr;
#pragma unroll
                for (int r = 0; r < 4; ++r)
                    atomicAdd(out + (size_t)(rr + r) * O_DIM + cc, acc[mt][nt][r]);
            }
    }
}

// ---------------------------------------------------------------------------
// Sum the KSPLIT_P partial buffers into out. 37.7 MB traffic, BW-bound.
__global__ __launch_bounds__(256) void reduce8(const float* __restrict__ parts,
                                               float* __restrict__ out) {
    constexpr int N4 = B_DIM * O_DIM / 4;
    int i = blockIdx.x * 256 + threadIdx.x;       // float4 index
    const float4* p = (const float4*)parts;
    float4 a = p[i];
#pragma unroll
    for (int z = 1; z < KSPLIT_P; ++z) {
        float4 b = p[(size_t)z * N4 + i];
        a.x += b.x; a.y += b.y; a.z += b.z; a.w += b.w;
    }
    ((float4*)out)[i] = a;
}

// ---------------------------------------------------------------------------
// Zero-workspace fallback (only if ws_size too small): correct but slow.
__global__ __launch_bounds__(256) void kan_fallback(const float* __restrict__ x,
                                                    const float* __restrict__ pw,
                                                    const float* __restrict__ bw,
                                                    const float* __restrict__ sw,
                                                    const float* __restrict__ sc,
                                                    float* __restrict__ out) {
    __shared__ float s_neg[J_DIM], s_pos[J_DIM], s_bas[J_DIM][5];
    __shared__ int s_k0[J_DIM];
    int b = blockIdx.x;
    int t = threadIdx.x;
#pragma unroll
    for (int jj = 0; jj < 2; ++jj) {
        int j = t + jj * 256;
        float xv = x[(size_t)b * J_DIM + j];
        float xc = fminf(fmaxf(xv, -1.f), 1.f);
        float pos = fmaxf(xc, 0.f);
        s_pos[j] = pos;
        s_neg[j] = xc - pos;
        int k0; float Nv[5];
        bspline5(xc, k0, Nv);
        s_k0[j] = k0;
#pragma unroll
        for (int r = 0; r < 5; ++r) s_bas[j][r] = Nv[r];
    }
    __syncthreads();
    for (int i = t; i < O_DIM; i += 256) {
        float acc = 0.f;
        for (int j = 0; j < J_DIM; ++j) {
            size_t ij = (size_t)i * J_DIM + j;
            float bwv = bw[ij];
            acc += bwv * (pw[ij] * s_neg[j] + s_pos[j]);
            int k0 = s_k0[j];
            const float* cp = sc + ij * 20;
            float sp = 0.f;
#pragma unroll
            for (int r = 0; r < 5; ++r) {
                int k = k0 + r;
                if (k >= 0) sp += s_bas[j][r] * cp[k];
            }
            acc += sw[ij] * sp;
        }
        out[(size_t)b * O_DIM + i] = acc;
    }
}

// ---------------------------------------------------------------------------
extern "C" void kernel_launch(void* const* d_in, const int* in_sizes, int n_in,
                              void* d_out, int out_size, void* d_ws, size_t ws_size,
                              hipStream_t stream) {
    const float* x  = (const float*)d_in[0];
    const float* pw = (const float*)d_in[1];
    const float* bw = (const float*)d_in[2];
    const float* sw = (const float*)d_in[3];
    const float* sc = (const float*)d_in[4];
    float* out = (float*)d_out;

    const size_t abct = (size_t)(B_DIM + O_DIM) * K_TOT * sizeof(half_t);       // 57.7 MB
    const size_t parts_bytes = (size_t)KSPLIT_P * B_DIM * O_DIM * sizeof(float); // 33.6 MB

    if (ws_size >= abct + parts_bytes) {
        // R5 path: non-atomic partials + reduce.
        half_t* A  = (half_t*)d_ws;
        half_t* Ct = A + (size_t)B_DIM * K_TOT;
        float* parts = (float*)((char*)d_ws + abct);   // 16B-aligned (abct % 16 == 0)

        prep_all<<<ZERO_BLKS + O_DIM + B_DIM, 256, 0, stream>>>(x, pw, bw, sw, sc, A, Ct, out);
        dim3 g(B_DIM / MTILE, O_DIM / NTILE, KSPLIT_P);   // (16, 4, 8)
        gemm_f16<KSPLIT_P, 0><<<g, 256, 0, stream>>>(A, Ct, parts);
        reduce8<<<(B_DIM * O_DIM / 4) / 256, 256, 0, stream>>>(parts, out);
    } else if (ws_size >= abct) {
        // Legacy atomic path (still gets the pipelined K-loop).
        half_t* A  = (half_t*)d_ws;
        half_t* Ct = A + (size_t)B_DIM * K_TOT;

        prep_all<<<ZERO_BLKS + O_DIM + B_DIM, 256, 0, stream>>>(x, pw, bw, sw, sc, A, Ct, out);
        dim3 g(B_DIM / MTILE, O_DIM / NTILE, KSPLIT_A);   // (16, 4, 11)
        gemm_f16<KSPLIT_A, 1><<<g, 256, 0, stream>>>(A, Ct, out);
    } else {
        kan_fallback<<<B_DIM, 256, 0, stream>>>(x, pw, bw, sw, sc, out);
    }
}

// Round 2
// 127.396 us; speedup vs baseline: 1.1188x; 1.0046x over previous
//
#include <hip/hip_runtime.h>

// KAN layer as one fused fp16 MFMA GEMM:
//   out[b,i] = sum_j [ neg*bw*pw + pos*bw + sum_k basis[b,j,k]*sw[i,j]*sc[i,j,k] ]
// A  [2048 x 11264] fp16 : per j, 22 slots = {20 basis (5 nonzero), neg, pos}
// Ct [ 512 x 11264] fp16 : per j, 22 slots = {sw*sc[0..19], bw*pw, bw}   (B^T layout)
// R6: XCD-aware swizzle — each of the 8 k-splits pinned to one XCD
//     (z = lid%8). R5 counters showed gemm at 20% Mfma / 30% HBM with
//     ~2330 cy/chunk: L3-BW-bound on ~368 MB of cross-XCD shared-operand
//     re-reads (Ct's 16 m-sharers were spread over all XCDs). Now each
//     XCD's 64 co-resident blocks share ONE A z-slice (5.77 MB, 4x reuse
//     in L2) + ONE Ct z-slice (1.44 MB, fits L2, 16x reuse).
//     Also: ZERO blocks skipped in partials path (reduce8 overwrites out).
// R5: KSPLIT=8 non-atomic partials + reduce8; 3-deep LDS pipeline with
//     counted vmcnt(4) + raw s_barrier (T3/T4), setprio around MFMA (T5).
// ws usage: A = 46.1 MB, Ct = 11.5 MB, partials = 33.6 MB (91.2 MB total).

typedef _Float16 half_t;
typedef __attribute__((ext_vector_type(8))) _Float16 half8;
typedef __attribute__((ext_vector_type(4))) float floatx4;

#define B_DIM   2048
#define J_DIM   512
#define O_DIM   512
#define SLOTS   22
#define K_TOT   (J_DIM * SLOTS)      // 11264
#define MTILE   128
#define NTILE   128
#define BK      32
#define KSPLIT_P 8                   // partials path (== NXCD, one z per XCD)
#define KSPLIT_A 11                  // atomic fallback path
#define ZERO_BLKS 64                 // blocks zeroing the 4 MB output (atomic path only)

// ---------------------------------------------------------------------------
// Quartic B-spline local basis, uniform knots g_i = -1.5 + i*(3.125/24).
// (Reference quirk: linspace(-1.5, 1.625, 25) -> spacing 3.125/24, NOT 0.125.)
// m in [3,19]; window k = m-4 .. m, entries with k<0 dropped.
__device__ __forceinline__ void bspline5(float xc, int& k0, float Nv[5]) {
    const float invS = 7.68f;              // 24/3.125 (exact ratio)
    float u = (xc + 1.5f) * invS;          // knot units
    int m = (int)u;
    m = min(max(m, 3), 19);
    k0 = m - 4;
    Nv[0] = 1.f; Nv[1] = 0.f; Nv[2] = 0.f; Nv[3] = 0.f; Nv[4] = 0.f;
#pragma unroll
    for (int d = 1; d <= 4; ++d) {
        float nw[5];
        float inv_d = 1.0f / (float)d;
#pragma unroll
        for (int r = 0; r < 5; ++r) {
            if (r > d) { nw[r] = 0.f; continue; }
            float kk = (float)(m - d + r);
            float acc = 0.f;
            if (r >= 1) acc += (u - kk) * Nv[r - 1];
            if (r < d)  acc += (kk + (float)(d + 1) - u) * Nv[r];
            nw[r] = acc * inv_d;
        }
#pragma unroll
        for (int r = 0; r < 5; ++r) Nv[r] = nw[r];
    }
}

// ---------------------------------------------------------------------------
// Fused prep: blocks [0,zb) zero the output; [zb, zb+512) build Ct rows;
// [zb+512, zb+512+2048) build A rows. zb=0 in partials path (out is fully
// overwritten by reduce8 — zeroing was pure waste there).
__global__ __launch_bounds__(256) void prep_all(const float* __restrict__ x,
                                                const float* __restrict__ pw,
                                                const float* __restrict__ bw,
                                                const float* __restrict__ sw,
                                                const float* __restrict__ sc,
                                                half_t* __restrict__ A,
                                                half_t* __restrict__ Ct,
                                                float* __restrict__ out,
                                                int zb) {
    __shared__ half_t rec[J_DIM * SLOTS];  // 22528 B
    int bid = blockIdx.x;
    int t = threadIdx.x;

    if (bid < zb) {
        float4* o = (float4*)out;
        int base = bid * 4096;
#pragma unroll
        for (int i = 0; i < 16; ++i)
            o[base + i * 256 + t] = make_float4(0.f, 0.f, 0.f, 0.f);
        return;
    }

    if (bid < zb + O_DIM) {
        // prep_C: fold spline_weight into coeffs + base slots. sc row is
        // 16B-aligned per (i,j): ij*20 floats = ij*80 B.
        int i = bid - zb;
#pragma unroll
        for (int jj = 0; jj < 2; ++jj) {
            int j = t + jj * 256;
            size_t ij = (size_t)i * J_DIM + j;
            float s = sw[ij], b = bw[ij], p = pw[ij];
            const float4* scp4 = (const float4*)(sc + ij * 20);
            half_t* r = rec + j * SLOTS;
#pragma unroll
            for (int v = 0; v < 5; ++v) {
                float4 c4 = scp4[v];
                r[v * 4 + 0] = (half_t)(s * c4.x);
                r[v * 4 + 1] = (half_t)(s * c4.y);
                r[v * 4 + 2] = (half_t)(s * c4.z);
                r[v * 4 + 3] = (half_t)(s * c4.w);
            }
            r[20] = (half_t)(b * p);
            r[21] = (half_t)b;
        }
        __syncthreads();
        const uint4* src = (const uint4*)rec;
        uint4* dst = (uint4*)(Ct + (size_t)i * K_TOT);
        for (int idx = t; idx < (J_DIM * SLOTS * 2) / 16; idx += 256) dst[idx] = src[idx];
        return;
    }

    // prep_A: basis record per (b, j)
    int b = bid - zb - O_DIM;
#pragma unroll
    for (int jj = 0; jj < 2; ++jj) {
        int j = t + jj * 256;
        float xv = x[(size_t)b * J_DIM + j];
        float xc = fminf(fmaxf(xv, -1.f), 1.f);
        float pos = fmaxf(xc, 0.f);
        float neg = xc - pos;
        int k0; float Nv[5];
        bspline5(xc, k0, Nv);
        half_t* r = rec + j * SLOTS;
#pragma unroll
        for (int k = 0; k < 20; ++k) r[k] = (half_t)0.f;
#pragma unroll
        for (int rr = 0; rr < 5; ++rr) {
            int k = k0 + rr;
            if (k >= 0) r[k] = (half_t)Nv[rr];   // k <= 19 guaranteed (k0 <= 15)
        }
        r[20] = (half_t)neg;
        r[21] = (half_t)pos;
    }
    __syncthreads();
    const uint4* src = (const uint4*)rec;
    uint4* dst = (uint4*)(A + (size_t)b * K_TOT);
    for (int i = t; i < (J_DIM * SLOTS * 2) / 16; i += 256) dst[i] = src[i];
}

// ---------------------------------------------------------------------------
// GEMM: Grid (16, 4, KSPLIT), 256 thr. 3-deep LDS pipeline:
//   prologue issues chunks 0,1; iter c waits vmcnt(4) (chunk c's 4 loads done,
//   chunk c+1's still flying), raw s_barrier, issues chunk c+2, then
//   ds_read + 16 MFMA under setprio(1). vmcnt never drains to 0 in the loop.
// XOR swizzle on the global source k-quad kills fragment-read conflicts (R3: 0).
// OUTMODE 0 (KSPLIT=8): XCD swizzle z = lid%8 — each XCD owns one k-split;
//   its 64 co-resident blocks share one A z-slice (4x L2 reuse) + one Ct
//   z-slice (1.44 MB, L2-resident, 16x reuse). Plain stores to partials.
// OUTMODE 1: legacy atomicAdd into out (ws-constrained fallback), no swizzle.
template<int KSPLIT_T, int OUTMODE>
__global__ __launch_bounds__(256, 3) void gemm_f16(const half_t* __restrict__ A,
                                                   const half_t* __restrict__ Bt,
                                                   float* __restrict__ out) {
    constexpr int KS_LEN_T = K_TOT / KSPLIT_T;
    constexpr int KCH_T = KS_LEN_T / BK;
    static_assert(KS_LEN_T % BK == 0, "k-split must be BK-aligned");
    static_assert(KCH_T >= 2, "pipeline needs >= 2 chunks");

    __shared__ half_t As[3][MTILE * BK];   // 3 x 8 KB
    __shared__ half_t Bs[3][NTILE * BK];   // 3 x 8 KB   (48 KB total -> 3 blk/CU cap)

    int bx, by, bz;
    if (OUTMODE == 0 && KSPLIT_T == 8) {
        // dispatch order is x-fastest: lid = x + 16*(y + 4*z); XCD = lid % 8.
        int lid = blockIdx.x + (B_DIM / MTILE) * (blockIdx.y + (O_DIM / NTILE) * blockIdx.z);
        bz = lid & 7;                    // one k-split per XCD
        int rem = lid >> 3;              // 0..63 within the XCD
        bx = rem & (B_DIM / MTILE - 1);  // 16 m-blocks
        by = rem >> 4;                   // 4 n-blocks
    } else {
        bx = blockIdx.x; by = blockIdx.y; bz = blockIdx.z;
    }

    int m0 = bx * MTILE;
    int n0 = by * NTILE;
    int ks = bz * KS_LEN_T;     // halfs; KS_LEN_T*2 B is 16B-aligned

    int t = threadIdx.x;
    int w = t >> 6;          // wave 0..3
    int l = t & 63;
    int wm = w >> 1, wn = w & 1;

    floatx4 acc[4][4] = {};

    int lrow = l >> 2;                            // 0..15: row within 16-row chunk
    int lkof = (((l & 3) ^ ((l >> 3) & 3)) * 8);  // swizzled k-quad source offset

    const half_t* gA = A + (size_t)m0 * K_TOT + ks;
    const half_t* gB = Bt + (size_t)n0 * K_TOT + ks;

    int q = l >> 4;               // 0..3
    int fr = l & 15;              // 0..15
    int qs = (q ^ ((fr >> 1) & 3)) * 8;  // swizzled read offset (elements)

// 4 global_load_lds per thread per chunk (2 A + 2 B) -> vmcnt counts in 4s.
#define ISSUE_LOADS(c, p)                                                     \
    {                                                                         \
        int kb = (c) * BK;                                                    \
        _Pragma("unroll")                                                     \
        for (int n = 0; n < 2; ++n) {                                         \
            int r = (w * 2 + n) * 16 + lrow;                                  \
            __builtin_amdgcn_global_load_lds(                                 \
                (const __attribute__((address_space(1))) unsigned int*)       \
                    (gA + (size_t)r * K_TOT + kb + lkof),                     \
                (__attribute__((address_space(3))) unsigned int*)             \
                    (&As[p][0] + (w * 2 + n) * 512),                          \
                16, 0, 0);                                                    \
            __builtin_amdgcn_global_load_lds(                                 \
                (const __attribute__((address_space(1))) unsigned int*)       \
                    (gB + (size_t)r * K_TOT + kb + lkof),                     \
                (__attribute__((address_space(3))) unsigned int*)             \
                    (&Bs[p][0] + (w * 2 + n) * 512),                          \
                16, 0, 0);                                                    \
        }                                                                     \
    }

    ISSUE_LOADS(0, 0)
    ISSUE_LOADS(1, 1)

    int pb = 0;                              // consume buffer = c % 3
    for (int c = 0; c < KCH_T; ++c) {
        if (c + 2 < KCH_T) {
            // 8 outstanding (c, c+1); keep c+1's 4 flying across the barrier.
            asm volatile("s_waitcnt vmcnt(4)" ::: "memory");
            __builtin_amdgcn_s_barrier();
            int pn = pb + 2; if (pn >= 3) pn -= 3;
            ISSUE_LOADS(c + 2, pn)
        } else if (c + 2 == KCH_T) {
            asm volatile("s_waitcnt vmcnt(4)" ::: "memory");
            __builtin_amdgcn_s_barrier();
        } else {
            asm volatile("s_waitcnt vmcnt(0)" ::: "memory");
            __builtin_amdgcn_s_barrier();
        }

        half8 af[4], bf[4];
#pragma unroll
        for (int mt = 0; mt < 4; ++mt)
            af[mt] = *(const half8*)(&As[pb][0] + (wm * 64 + mt * 16 + fr) * BK + qs);
#pragma unroll
        for (int nt = 0; nt < 4; ++nt)
            bf[nt] = *(const half8*)(&Bs[pb][0] + (wn * 64 + nt * 16 + fr) * BK + qs);

        __builtin_amdgcn_s_setprio(1);
#pragma unroll
        for (int mt = 0; mt < 4; ++mt)
#pragma unroll
            for (int nt = 0; nt < 4; ++nt)
                acc[mt][nt] = __builtin_amdgcn_mfma_f32_16x16x32_f16(
                    af[mt], bf[nt], acc[mt][nt], 0, 0, 0);
        __builtin_amdgcn_s_setprio(0);

        if (++pb == 3) pb = 0;
    }
#undef ISSUE_LOADS

    // epilogue: C/D layout col = lane&15, row = (lane>>4)*4 + reg (m89-verified)
    if (OUTMODE == 0) {
        float* dst = out + (size_t)bz * ((size_t)B_DIM * O_DIM);
#pragma unroll
        for (int mt = 0; mt < 4; ++mt)
#pragma unroll
            for (int nt = 0; nt < 4; ++nt) {
                int rr = m0 + wm * 64 + mt * 16 + q * 4;
                int cc = n0 + wn * 64 + nt * 16 + fr;
#pragma unroll
                for (int r = 0; r < 4; ++r)
                    dst[(size_t)(rr + r) * O_DIM + cc] = acc[mt][nt][r];
            }
    } else {
#pragma unroll
        for (int mt = 0; mt < 4; ++mt)
#pragma unroll
            for (int nt = 0; nt < 4; ++nt) {
                int rr = m0 + wm * 64 + mt * 16 + q * 4;
                int cc = n0 + wn * 64 + nt * 16 + fr;
#pragma unroll
                for (int r = 0; r < 4; ++r)
                    atomicAdd(out + (size_t)(rr + r) * O_DIM + cc, acc[mt][nt][r]);
            }
    }
}

// ---------------------------------------------------------------------------
// Sum the KSPLIT_P partial buffers into out. 37.7 MB traffic, BW-bound.
__global__ __launch_bounds__(256) void reduce8(const float* __restrict__ parts,
                                               float* __restrict__ out) {
    constexpr int N4 = B_DIM * O_DIM / 4;
    int i = blockIdx.x * 256 + threadIdx.x;       // float4 index
    const float4* p = (const float4*)parts;
    float4 a = p[i];
#pragma unroll
    for (int z = 1; z < KSPLIT_P; ++z) {
        float4 b = p[(size_t)z * N4 + i];
        a.x += b.x; a.y += b.y; a.z += b.z; a.w += b.w;
    }
    ((float4*)out)[i] = a;
}

// ---------------------------------------------------------------------------
// Zero-workspace fallback (only if ws_size too small): correct but slow.
__global__ __launch_bounds__(256) void kan_fallback(const float* __restrict__ x,
                                                    const float* __restrict__ pw,
                                                    const float* __restrict__ bw,
                                                    const float* __restrict__ sw,
                                                    const float* __restrict__ sc,
                                                    float* __restrict__ out) {
    __shared__ float s_neg[J_DIM], s_pos[J_DIM], s_bas[J_DIM][5];
    __shared__ int s_k0[J_DIM];
    int b = blockIdx.x;
    int t = threadIdx.x;
#pragma unroll
    for (int jj = 0; jj < 2; ++jj) {
        int j = t + jj * 256;
        float xv = x[(size_t)b * J_DIM + j];
        float xc = fminf(fmaxf(xv, -1.f), 1.f);
        float pos = fmaxf(xc, 0.f);
        s_pos[j] = pos;
        s_neg[j] = xc - pos;
        int k0; float Nv[5];
        bspline5(xc, k0, Nv);
        s_k0[j] = k0;
#pragma unroll
        for (int r = 0; r < 5; ++r) s_bas[j][r] = Nv[r];
    }
    __syncthreads();
    for (int i = t; i < O_DIM; i += 256) {
        float acc = 0.f;
        for (int j = 0; j < J_DIM; ++j) {
            size_t ij = (size_t)i * J_DIM + j;
            float bwv = bw[ij];
            acc += bwv * (pw[ij] * s_neg[j] + s_pos[j]);
            int k0 = s_k0[j];
            const float* cp = sc + ij * 20;
            float sp = 0.f;
#pragma unroll
            for (int r = 0; r < 5; ++r) {
                int k = k0 + r;
                if (k >= 0) sp += s_bas[j][r] * cp[k];
            }
            acc += sw[ij] * sp;
        }
        out[(size_t)b * O_DIM + i] = acc;
    }
}

// ---------------------------------------------------------------------------
extern "C" void kernel_launch(void* const* d_in, const int* in_sizes, int n_in,
                              void* d_out, int out_size, void* d_ws, size_t ws_size,
                              hipStream_t stream) {
    const float* x  = (const float*)d_in[0];
    const float* pw = (const float*)d_in[1];
    const float* bw = (const float*)d_in[2];
    const float* sw = (const float*)d_in[3];
    const float* sc = (const float*)d_in[4];
    float* out = (float*)d_out;

    const size_t abct = (size_t)(B_DIM + O_DIM) * K_TOT * sizeof(half_t);       // 57.7 MB
    const size_t parts_bytes = (size_t)KSPLIT_P * B_DIM * O_DIM * sizeof(float); // 33.6 MB

    if (ws_size >= abct + parts_bytes) {
        // R6 path: non-atomic partials + reduce, XCD-pinned k-splits.
        half_t* A  = (half_t*)d_ws;
        half_t* Ct = A + (size_t)B_DIM * K_TOT;
        float* parts = (float*)((char*)d_ws + abct);   // 16B-aligned (abct % 16 == 0)

        prep_all<<<O_DIM + B_DIM, 256, 0, stream>>>(x, pw, bw, sw, sc, A, Ct, out, 0);
        dim3 g(B_DIM / MTILE, O_DIM / NTILE, KSPLIT_P);   // (16, 4, 8)
        gemm_f16<KSPLIT_P, 0><<<g, 256, 0, stream>>>(A, Ct, parts);
        reduce8<<<(B_DIM * O_DIM / 4) / 256, 256, 0, stream>>>(parts, out);
    } else if (ws_size >= abct) {
        // Legacy atomic path (still gets the pipelined K-loop).
        half_t* A  = (half_t*)d_ws;
        half_t* Ct = A + (size_t)B_DIM * K_TOT;

        prep_all<<<ZERO_BLKS + O_DIM + B_DIM, 256, 0, stream>>>(x, pw, bw, sw, sc, A, Ct, out,
                                                                ZERO_BLKS);
        dim3 g(B_DIM / MTILE, O_DIM / NTILE, KSPLIT_A);   // (16, 4, 11)
        gemm_f16<KSPLIT_A, 1><<<g, 256, 0, stream>>>(A, Ct, out);
    } else {
        kan_fallback<<<B_DIM, 256, 0, stream>>>(x, pw, bw, sw, sc, out);
    }
}